// Round 13
// baseline (1605.777 us; speedup 1.0000x reference)
//
#include <hip/hip_runtime.h>
#include <stdint.h>
#include <stdio.h>

#define T_TOK 8192
#define HDIM  1024
#define IDIM  3584
#define NEXP  8
#define NPAIR (T_TOK*2)
#define BK 32

typedef float          f32x4 __attribute__((ext_vector_type(4)));
typedef short          s16x8 __attribute__((ext_vector_type(8)));
typedef unsigned short u16x4 __attribute__((ext_vector_type(4)));
typedef unsigned short u16x8 __attribute__((ext_vector_type(8)));

__device__ __forceinline__ unsigned short f2bf_rne(float f) {
  unsigned u = __float_as_uint(f);
  u += 0x7FFFu + ((u >> 16) & 1u);
  return (unsigned short)(u >> 16);
}
__device__ __forceinline__ float bf2f(unsigned short h) {
  return __uint_as_float(((unsigned)h) << 16);
}

__device__ __forceinline__ void gld16(const void* gsrc, void* ldst) {
  typedef const unsigned int __attribute__((address_space(1))) GU;
  typedef unsigned int       __attribute__((address_space(3))) LU;
  __builtin_amdgcn_global_load_lds((GU*)(unsigned long long)gsrc,
                                   (LU*)(unsigned int)(unsigned long long)ldst,
                                   16, 0, 0);
}

// ---- shared top-2 helper (stable, lowest-index tie-break like lax.top_k)
__device__ __forceinline__ void top2_write(const float* acc, int t,
                                           int* __restrict__ topi,
                                           float* __restrict__ topw) {
  int i0 = 0; float l0 = acc[0];
#pragma unroll
  for (int e = 1; e < NEXP; e++) if (acc[e] > l0) { l0 = acc[e]; i0 = e; }
  int i1 = -1; float l1 = -3.4e38f;
#pragma unroll
  for (int e = 0; e < NEXP; e++) if (e != i0 && acc[e] > l1) { l1 = acc[e]; i1 = e; }
  float w0 = 1.f/(1.f + expf(l1 - l0));
  float w1 = 1.f/(1.f + expf(l0 - l1));
  topi[2*t]   = i0; topi[2*t+1] = i1;
  topw[2*t]   = w0; topw[2*t+1] = w1;
}

// ===== K1: FUSED x split (hi/lo) + gate/up routers (one pass over x) ======
__global__ __launch_bounds__(256) void split_router(
    const float* __restrict__ X,
    const float* __restrict__ RWg, const float* __restrict__ RWu,
    unsigned short* __restrict__ xhi, unsigned short* __restrict__ xlo,
    int* __restrict__ tig, float* __restrict__ twg,
    int* __restrict__ tiu, float* __restrict__ twu) {
  int lane = threadIdx.x & 63;
  int t = blockIdx.x*4 + (threadIdx.x>>6);
  const f32x4* xr = (const f32x4*)(X + (long)t*HDIM);
  u16x4* hr = (u16x4*)(xhi + (long)t*HDIM);
  u16x4* lr = (u16x4*)(xlo + (long)t*HDIM);
  float ag[NEXP], au[NEXP];
#pragma unroll
  for (int e = 0; e < NEXP; e++) { ag[e] = 0.f; au[e] = 0.f; }
#pragma unroll
  for (int it = 0; it < HDIM/4/64; it++) {   // 4
    int c4 = it*64 + lane;
    f32x4 xv = xr[c4];
    u16x4 hh, ll;
#pragma unroll
    for (int j = 0; j < 4; j++) {
      unsigned short hb = f2bf_rne(xv[j]);
      hh[j] = hb;
      ll[j] = f2bf_rne(xv[j] - bf2f(hb));
    }
    hr[c4] = hh; lr[c4] = ll;
#pragma unroll
    for (int j = 0; j < 4; j++) {
      const float* wg = RWg + (long)(c4*4+j)*NEXP;
      const float* wu = RWu + (long)(c4*4+j)*NEXP;
#pragma unroll
      for (int e = 0; e < NEXP; e++) { ag[e] += xv[j]*wg[e]; au[e] += xv[j]*wu[e]; }
    }
  }
#pragma unroll
  for (int e = 0; e < NEXP; e++) {
    float vg = ag[e], vu = au[e];
#pragma unroll
    for (int o = 1; o < 64; o <<= 1) { vg += __shfl_xor(vg, o); vu += __shfl_xor(vu, o); }
    ag[e] = vg; au[e] = vu;
  }
  if (lane == 0) { top2_write(ag, t, tig, twg); top2_write(au, t, tiu, twu); }
}

// ===== K2: ALL-IN-ONE vectorized transpose (gate, up, down in one grid) ===
__global__ void transpose_split3(const float* __restrict__ gex,
                                 unsigned short* __restrict__ wg_hi,
                                 unsigned short* __restrict__ wg_lo,
                                 const float* __restrict__ uex,
                                 unsigned short* __restrict__ wu_hi,
                                 unsigned short* __restrict__ wu_lo,
                                 const float* __restrict__ dex,
                                 unsigned short* __restrict__ wd_hi) {
  __shared__ float t[32][33];
  int z = blockIdx.z;
  const float* W; unsigned short *hi, *lo; int K, N, k0, n0;
  if (z < NEXP)        { W = gex; hi = wg_hi; lo = wg_lo; K = HDIM; N = IDIM;
                         n0 = blockIdx.x*32; k0 = blockIdx.y*32; }
  else if (z < 2*NEXP) { W = uex; hi = wu_hi; lo = wu_lo; K = HDIM; N = IDIM;
                         n0 = blockIdx.x*32; k0 = blockIdx.y*32; }
  else                 { W = dex; hi = wd_hi; lo = nullptr; K = IDIM; N = HDIM;
                         k0 = blockIdx.x*32; n0 = blockIdx.y*32; }
  long base = (long)(z & 7) * K * N;
  int id = threadIdx.y*8 + threadIdx.x;
  int lrr = id >> 3, lcq = id & 7;
  f32x4 v = *(const f32x4*)&W[base + (long)(k0+lrr)*N + n0 + lcq*4];
  t[lrr][lcq*4+0] = v[0]; t[lrr][lcq*4+1] = v[1];
  t[lrr][lcq*4+2] = v[2]; t[lrr][lcq*4+3] = v[3];
  __syncthreads();
  int n = threadIdx.y, kq = threadIdx.x;
  u16x4 h, l;
#pragma unroll
  for (int r = 0; r < 4; r++) {
    float f = t[kq*4+r][n];
    unsigned short hb = f2bf_rne(f);
    h[r] = hb;
    l[r] = f2bf_rne(f - bf2f(hb));
  }
  long o = base + (long)(n0+n)*K + k0 + kq*4;
  *(u16x4*)&hi[o] = h;
  if (lo) *(u16x4*)&lo[o] = l;
}

// ===== K4: deterministic stable per-expert compaction ====================
__device__ __forceinline__ void perm_body(const int* __restrict__ topi,
                                          const float* __restrict__ topw,
                                          int* __restrict__ offs,
                                          int* __restrict__ ptok,
                                          float* __restrict__ pw, int e) {
  int tid = threadIdx.x, lane = tid & 63, wv = tid >> 6;
  __shared__ int cnt[NEXP];
  __shared__ int wsum[4];
  if (tid < NEXP) cnt[tid] = 0;
  __syncthreads();
  for (int p = tid; p < NPAIR; p += 256) atomicAdd(&cnt[topi[p]], 1);
  __syncthreads();
  int base = 0;
#pragma unroll
  for (int e2 = 0; e2 < NEXP; e2++) if (e2 < e) base += cnt[e2];
  if (tid == 0) { offs[e] = base; if (e == NEXP-1) offs[NEXP] = base + cnt[e]; }
  for (int p0 = 0; p0 < NPAIR; p0 += 256) {
    int p = p0 + tid;
    bool m = (topi[p] == e);
    unsigned long long b = __ballot(m);
    int lp = __popcll(b & ((1ull << lane) - 1ull));
    if (lane == 0) wsum[wv] = __popcll(b);
    __syncthreads();
    int woff = 0;
#pragma unroll
    for (int w2 = 0; w2 < 4; w2++) if (w2 < wv) woff += wsum[w2];
    int tot = wsum[0] + wsum[1] + wsum[2] + wsum[3];
    if (m) { int dst = base + woff + lp; ptok[dst] = p >> 1; pw[dst] = topw[p]; }
    base += tot;
    __syncthreads();
  }
}
__global__ __launch_bounds__(256) void build_perm(const int* topi, const float* topw,
                                                  int* offs, int* ptok, float* pw) {
  perm_body(topi, topw, offs, ptok, pw, blockIdx.x);
}
__global__ __launch_bounds__(256) void build_perm2(
    const int* tig, const float* twg, int* offsg, int* ptokg, float* pwg,
    const int* tiu, const float* twu, int* offsu, int* ptoku, float* pwu) {
  if (blockIdx.x < NEXP) perm_body(tig, twg, offsg, ptokg, pwg, blockIdx.x);
  else                   perm_body(tiu, twu, offsu, ptoku, pwu, blockIdx.x - NEXP);
}

// ===== K5: gathered 3-term GEMM, 256x256, SINGLE-BUFFER + reg prefetch ====
// Round-13: TLP attack. LDS 133KB->67KB => 2 blocks/CU (4 waves/SIMD) so a
// second block's MFMA bursts fill this block's stall slots (m114 overlap).
// Tile t+1 prefetched into REGISTERS (8x global_load_dwordx4, issued before
// tile t's MFMA: T14), ds_write_b128 into the single buffer between two
// barriers. Same pre-swizzled layout, values, and 3-term MFMA order as R12
// -> bit-identical output. Writes are contiguous-1KB per wave (full BW).
__global__ __launch_bounds__(512) void moe_gemm3_sb(
    const unsigned short* __restrict__ Ahi, const unsigned short* __restrict__ Alo,
    const unsigned short* __restrict__ Bhi, const unsigned short* __restrict__ Blo,
    const int* __restrict__ offs, const int* __restrict__ ptok,
    const float* __restrict__ pw, float* __restrict__ out)
{
  const int e = blockIdx.z;
  const int beg = offs[e];
  const int cnt = offs[e+1] - beg;
  const int m0 = blockIdx.y * 256;   // NO XCD swizzle (round-3 lesson)
  if (m0 >= cnt) return;
  const int n0 = blockIdx.x * 256;

  __shared__ unsigned short As[2][256*32];   // [hi/lo] 32 KB
  __shared__ unsigned short Bs[2][256*32];   // 32 KB  -> 2 blocks/CU
  __shared__ int   stok[256];
  __shared__ float swt[256];

  const int tid = threadIdx.x, lane = tid & 63, wv = tid >> 6;
  if (tid < 256) {
    int i = m0 + tid;
    stok[tid] = ptok[beg + (i < cnt ? i : 0)];
    swt[tid]  = (i < cnt) ? pw[beg + i] : 0.f;
  }
  __syncthreads();

  const int srow = lane >> 2;
  const int lc   = ((lane & 3) - ((lane >> 3) & 3)) & 3;  // pre-swizzled src
  const long aoff0 = (long)stok[wv*32 +      srow]*HDIM + lc*8;
  const long aoff1 = (long)stok[wv*32 + 16 + srow]*HDIM + lc*8;
  const long boff0 = ((long)e*IDIM + n0 + wv*32 +      srow)*HDIM + lc*8;
  const long boff1 = ((long)e*IDIM + n0 + wv*32 + 16 + srow)*HDIM + lc*8;
  // lane's 16B lands at (wave slab base + lane*8 shorts) — matches gld16 layout
  const int wdst0 = (wv*32     )*32 + lane*8;
  const int wdst1 = (wv*32 + 16)*32 + lane*8;

  u16x8 ra0, ra1, ra2, ra3, rb0, rb1, rb2, rb3;   // tile prefetch regs (32 VGPR)

#define LOADR(kk) do { int kl_ = (kk)*32;                        \
    ra0 = *(const u16x8*)(Ahi + aoff0 + kl_);                    \
    ra1 = *(const u16x8*)(Ahi + aoff1 + kl_);                    \
    ra2 = *(const u16x8*)(Alo + aoff0 + kl_);                    \
    ra3 = *(const u16x8*)(Alo + aoff1 + kl_);                    \
    rb0 = *(const u16x8*)(Bhi + boff0 + kl_);                    \
    rb1 = *(const u16x8*)(Bhi + boff1 + kl_);                    \
    rb2 = *(const u16x8*)(Blo + boff0 + kl_);                    \
    rb3 = *(const u16x8*)(Blo + boff1 + kl_);                    \
  } while (0)
#define WRITE_LDS() do {                                         \
    *(u16x8*)&As[0][wdst0] = ra0;  *(u16x8*)&As[0][wdst1] = ra1; \
    *(u16x8*)&As[1][wdst0] = ra2;  *(u16x8*)&As[1][wdst1] = ra3; \
    *(u16x8*)&Bs[0][wdst0] = rb0;  *(u16x8*)&Bs[0][wdst1] = rb1; \
    *(u16x8*)&Bs[1][wdst0] = rb2;  *(u16x8*)&Bs[1][wdst1] = rb3; \
  } while (0)

  const int fl = lane & 15, fg = lane >> 4;
  const int pks = (((fg + (fl >> 1)) & 3) << 3);
  const int wm = wv >> 2, wn = wv & 3;   // 2M x 4N wave grid
  const int arow = wm * 128;
  const int bcol = wn * 64;

  f32x4 acc[8][4];
#pragma unroll
  for (int m = 0; m < 8; m++)
#pragma unroll
    for (int n = 0; n < 4; n++) acc[m][n] = {0.f, 0.f, 0.f, 0.f};

  LOADR(0);
  WRITE_LDS();
  __syncthreads();   // tile 0 visible

  for (int kt = 0; kt < HDIM/BK; ++kt) {   // 32 K-tiles
    const bool st = (kt + 1 < HDIM/BK);
    if (st) LOADR(kt + 1);   // T14: issue next tile's loads under this compute

    s16x8 ahf[8], bhi4[4], blo4[4];
    // phase A: read Ahi[8]+Bhi[4]+Blo[4] | 32 MFMA hi*hi
#pragma unroll
    for (int n = 0; n < 4; n++)
      bhi4[n] = *(const s16x8*)&Bs[0][(bcol + n*16 + fl)*32 + pks];
#pragma unroll
    for (int n = 0; n < 4; n++)
      blo4[n] = *(const s16x8*)&Bs[1][(bcol + n*16 + fl)*32 + pks];
#pragma unroll
    for (int i = 0; i < 8; i++)
      ahf[i] = *(const s16x8*)&As[0][(arow + i*16 + fl)*32 + pks];
    __builtin_amdgcn_s_setprio(1);
#pragma unroll
    for (int i = 0; i < 8; i++)
#pragma unroll
      for (int n = 0; n < 4; n++)
        acc[i][n] = __builtin_amdgcn_mfma_f32_16x16x32_bf16(ahf[i], bhi4[n], acc[i][n], 0,0,0);
    __builtin_amdgcn_s_setprio(0);

    // phase B: 32 MFMA hi*lo (regs live, no reads)
    __builtin_amdgcn_s_setprio(1);
#pragma unroll
    for (int i = 0; i < 8; i++)
#pragma unroll
      for (int n = 0; n < 4; n++)
        acc[i][n] = __builtin_amdgcn_mfma_f32_16x16x32_bf16(ahf[i], blo4[n], acc[i][n], 0,0,0);
    __builtin_amdgcn_s_setprio(0);

    // phase C: read Alo[8] (reuse ahf regs) | 32 MFMA lo*hi
#pragma unroll
    for (int i = 0; i < 8; i++)
      ahf[i] = *(const s16x8*)&As[1][(arow + i*16 + fl)*32 + pks];
    __builtin_amdgcn_s_setprio(1);
#pragma unroll
    for (int i = 0; i < 8; i++)
#pragma unroll
      for (int n = 0; n < 4; n++)
        acc[i][n] = __builtin_amdgcn_mfma_f32_16x16x32_bf16(ahf[i], bhi4[n], acc[i][n], 0,0,0);
    __builtin_amdgcn_s_setprio(0);

    __syncthreads();                       // all reads of tile kt done
    if (st) { WRITE_LDS(); __syncthreads(); }   // tile kt+1 written + visible
  }
#undef LOADR
#undef WRITE_LDS

  // epilogue: C/D map col=lane&15, row=(lane>>4)*4+r  [m89/m91-verified]
#pragma unroll
  for (int m = 0; m < 8; m++)
#pragma unroll
    for (int r = 0; r < 4; r++) {
      int lrow = arow + m*16 + fg*4 + r;
      if (m0 + lrow < cnt) {
        float wt = swt[lrow];
        long ob = (long)stok[lrow]*IDIM + n0 + bcol + fl;
#pragma unroll
        for (int n = 0; n < 4; n++)
          atomicAdd(&out[ob + n*16], wt * acc[m][n][r]);
      }
    }
}

// ===== K6: fused SwiGLU + down-router; writes h as bf16 (RNE) =============
__global__ __launch_bounds__(256) void swiglu_router_bf(
    const float* __restrict__ g, const float* __restrict__ u,
    unsigned short* __restrict__ hb,
    const float* __restrict__ RW,
    int* __restrict__ topi, float* __restrict__ topw) {
  int lane = threadIdx.x & 63;
  int t = blockIdx.x*4 + (threadIdx.x>>6);
  const f32x4* gr = (const f32x4*)(g + (long)t*IDIM);
  const f32x4* ur = (const f32x4*)(u + (long)t*IDIM);
  u16x4*       hr = (u16x4*)(hb + (long)t*IDIM);
  float acc[NEXP];
#pragma unroll
  for (int e = 0; e < NEXP; e++) acc[e] = 0.f;
#pragma unroll
  for (int it = 0; it < IDIM/4/64; it++) {   // 14
    int c4 = it*64 + lane;
    f32x4 gv = gr[c4], uv = ur[c4], hv;
    u16x4 hh;
#pragma unroll
    for (int j = 0; j < 4; j++) {
      float x = gv[j];
      hv[j] = x * uv[j] / (1.f + expf(-x));
      hh[j] = f2bf_rne(hv[j]);
    }
    hr[c4] = hh;
#pragma unroll
    for (int j = 0; j < 4; j++) {
      const float* wr = RW + (long)(c4*4+j)*NEXP;
#pragma unroll
      for (int e = 0; e < NEXP; e++) acc[e] += hv[j]*wr[e];
    }
  }
#pragma unroll
  for (int e = 0; e < NEXP; e++) {
    float v = acc[e];
#pragma unroll
    for (int o = 1; o < 64; o <<= 1) v += __shfl_xor(v, o);
    acc[e] = v;
  }
  if (lane == 0) top2_write(acc, t, topi, topw);
}

// ===== K7: down GEMM, both operands bf16 gld16-staged, dbuf + swizzle =====
__global__ __launch_bounds__(256) void moe_gemm_down_bf(
    const unsigned short* __restrict__ Hb, const unsigned short* __restrict__ Bw,
    const int* __restrict__ offs, const int* __restrict__ ptok,
    const float* __restrict__ pw, float* __restrict__ out)
{
  const int K = IDIM, N = HDIM;
  const int e = blockIdx.z;
  const int beg = offs[e];
  const int cnt = offs[e+1] - beg;
  const int m0 = blockIdx.y * 128;   // NO swizzle
  if (m0 >= cnt) return;
  const int n0 = blockIdx.x * 128;

  __shared__ unsigned short As[2][128*32], Bs[2][128*32];  // 32KB dbuf
  __shared__ int   stok[128];
  __shared__ float swt[128];

  const int tid = threadIdx.x, lane = tid & 63, wv = tid >> 6;  // 4 waves
  if (tid < 128) {
    int i = m0 + tid;
    stok[tid] = ptok[beg + (i < cnt ? i : 0)];
    swt[tid]  = (i < cnt) ? pw[beg + i] : 0.f;
  }
  __syncthreads();

  const int srow = lane >> 2;
  const int lc   = ((lane & 3) - ((lane >> 3) & 3)) & 3;
  const long aoff0 = (long)stok[wv*32 +      srow]*K + lc*8;
  const long aoff1 = (long)stok[wv*32 + 16 + srow]*K + lc*8;
  const long boff0 = ((long)e*N + n0 + wv*32 +      srow)*K + lc*8;
  const long boff1 = ((long)e*N + n0 + wv*32 + 16 + srow)*K + lc*8;
  const int dst0 = (wv*32     )*32;
  const int dst1 = (wv*32 + 16)*32;

#define STAGE(buf, kt) do {                                 \
    int kl_ = (kt)*32;                                      \
    gld16(Hb + aoff0 + kl_, &As[buf][dst0]);                \
    gld16(Hb + aoff1 + kl_, &As[buf][dst1]);                \
    gld16(Bw + boff0 + kl_, &Bs[buf][dst0]);                \
    gld16(Bw + boff1 + kl_, &Bs[buf][dst1]);                \
  } while (0)

  const int fl = lane & 15, fg = lane >> 4;
  const int pks = (((fg + (fl >> 1)) & 3) << 3);
  const int arow = (wv >> 1)*64, bcol = (wv & 1)*64;

  f32x4 acc[4][4];
#pragma unroll
  for (int m = 0; m < 4; m++)
#pragma unroll
    for (int n = 0; n < 4; n++) acc[m][n] = {0.f, 0.f, 0.f, 0.f};

  STAGE(0, 0);
  __syncthreads();

  int cur = 0;
  for (int kt = 0; kt < K/BK; ++kt) {   // 112
    if (kt + 1 < K/BK) STAGE(cur^1, kt + 1);

    s16x8 ahf[4], bhf[4];
#pragma unroll
    for (int i = 0; i < 4; i++) {
      ahf[i] = *(const s16x8*)&As[cur][(arow + i*16 + fl)*32 + pks];
      bhf[i] = *(const s16x8*)&Bs[cur][(bcol + i*16 + fl)*32 + pks];
    }
    __builtin_amdgcn_s_setprio(1);
#pragma unroll
    for (int i = 0; i < 4; i++)
#pragma unroll
      for (int n = 0; n < 4; n++)
        acc[i][n] = __builtin_amdgcn_mfma_f32_16x16x32_bf16(ahf[i], bhf[n], acc[i][n], 0,0,0);
    __builtin_amdgcn_s_setprio(0);

    __syncthreads();
    cur ^= 1;
  }
#undef STAGE

#pragma unroll
  for (int m = 0; m < 4; m++)
#pragma unroll
    for (int r = 0; r < 4; r++) {
      int lrow = arow + m*16 + fg*4 + r;
      if (m0 + lrow < cnt) {
        float wt = swt[lrow];
        long ob = (long)stok[lrow]*N + n0 + bcol + fl;
#pragma unroll
        for (int n = 0; n < 4; n++)
          atomicAdd(&out[ob + n*16], wt * acc[m][n][r]);
      }
    }
}

// ========================== host launcher =================================
// Workspace plan (469.8MB avail; peak ~445.6MB). Aliases:
//   ubuf (f32, 117.4MB) = wg_hi+wg_lo region — memset AFTER gate GEMM.
//   hbuf (bf16, 58.7MB) = wu_lo — written by swiglu AFTER up GEMM.
extern "C" void kernel_launch(void* const* d_in, const int* in_sizes, int n_in,
                              void* d_out, int out_size, void* d_ws, size_t ws_size,
                              hipStream_t stream)
{
  (void)in_sizes; (void)n_in;
  const float* x   = (const float*)d_in[0];
  const float* grt = (const float*)d_in[1];
  const float* gex = (const float*)d_in[2];
  const float* urt = (const float*)d_in[3];
  const float* uex = (const float*)d_in[4];
  const float* drt = (const float*)d_in[5];
  const float* dex = (const float*)d_in[6];
  float* out = (float*)d_out;

  char* base = (char*)d_ws;
  size_t off = 0;
  auto alloc = [&](size_t b) -> void* {
    void* r = base + off;
    off = (off + b + 255) & ~(size_t)255;
    return r;
  };
  const size_t szXH = (size_t)T_TOK*HDIM*2;          // 16.78 MB
  const size_t szW  = (size_t)NEXP*HDIM*IDIM*2;      // 58.72 MB
  const size_t szGI = (size_t)T_TOK*IDIM*4;          // 117.44 MB

  unsigned short* xhi   = (unsigned short*)alloc(szXH);
  unsigned short* xlo   = (unsigned short*)alloc(szXH);
  unsigned short* wg_hi = (unsigned short*)alloc(szW);   // later: ubuf (f32)
  unsigned short* wg_lo = (unsigned short*)alloc(szW);
  unsigned short* wu_hi = (unsigned short*)alloc(szW);
  unsigned short* wu_lo = (unsigned short*)alloc(szW);   // later: hbuf (bf16)
  unsigned short* wd_hi = (unsigned short*)alloc(szW);
  float* gbuf = (float*)alloc(szGI);
  int*   topi_g = (int*)alloc(NPAIR*4);  float* topw_g = (float*)alloc(NPAIR*4);
  int*   topi_u = (int*)alloc(NPAIR*4);  float* topw_u = (float*)alloc(NPAIR*4);
  int*   topi_d = (int*)alloc(NPAIR*4);  float* topw_d = (float*)alloc(NPAIR*4);
  int* offs_g = (int*)alloc(64);
  int* offs_u = (int*)alloc(64);
  int* offs_d = (int*)alloc(64);
  int*   ptok_g = (int*)alloc(NPAIR*4);  float* pw_g = (float*)alloc(NPAIR*4);
  int*   ptok_u = (int*)alloc(NPAIR*4);  float* pw_u = (float*)alloc(NPAIR*4);
  int*   ptok_d = (int*)alloc(NPAIR*4);  float* pw_d = (float*)alloc(NPAIR*4);

  float*          ubuf = (float*)wg_hi;   // spans wg_hi+wg_lo (contiguous)
  unsigned short* hbuf = wu_lo;

  if (off > ws_size) {
    fprintf(stderr, "[moe] ws too small: need %zu bytes, have %zu\n", off, ws_size);
    hipMemsetAsync(d_out, 0, (size_t)out_size*sizeof(float), stream);
    return;
  }

  hipMemsetAsync(gbuf, 0, szGI, stream);
  hipMemsetAsync(d_out, 0, (size_t)out_size*sizeof(float), stream);

  transpose_split3<<<dim3(IDIM/32, HDIM/32, 3*NEXP), dim3(8,32), 0, stream>>>(
      gex, wg_hi, wg_lo, uex, wu_hi, wu_lo, dex, wd_hi);
  split_router<<<T_TOK/4, 256, 0, stream>>>(x, grt, urt, xhi, xlo,
                                            topi_g, topw_g, topi_u, topw_u);
  build_perm2<<<2*NEXP, 256, 0, stream>>>(topi_g, topw_g, offs_g, ptok_g, pw_g,
                                          topi_u, topw_u, offs_u, ptok_u, pw_u);

  // gate GEMM (last reader of wg region)
  moe_gemm3_sb<<<dim3(IDIM/256, 32, NEXP), 512, 0, stream>>>(
      xhi, xlo, wg_hi, wg_lo, offs_g, ptok_g, pw_g, gbuf);

  // wg region dead -> ubuf
  hipMemsetAsync(ubuf, 0, szGI, stream);
  moe_gemm3_sb<<<dim3(IDIM/256, 32, NEXP), 512, 0, stream>>>(
      xhi, xlo, wu_hi, wu_lo, offs_u, ptok_u, pw_u, ubuf);

  // fused: h = silu(g)*u -> bf16 hbuf + down-router top2 (on exact f32 h)
  swiglu_router_bf<<<T_TOK/4, 256, 0, stream>>>(gbuf, ubuf, hbuf, drt, topi_d, topw_d);
  build_perm<<<NEXP, 256, 0, stream>>>(topi_d, topw_d, offs_d, ptok_d, pw_d);

  moe_gemm_down_bf<<<dim3(HDIM/128, 64, NEXP), 256, 0, stream>>>(
      hbuf, wd_hi, offs_d, ptok_d, pw_d, out);
}

// Round 14
// 1535.666 us; speedup vs baseline: 1.0457x; 1.0457x over previous
//
#include <hip/hip_runtime.h>
#include <stdint.h>
#include <stdio.h>

#define T_TOK 8192
#define HDIM  1024
#define IDIM  3584
#define NEXP  8
#define NPAIR (T_TOK*2)
#define BK 32

typedef float          f32x4 __attribute__((ext_vector_type(4)));
typedef short          s16x8 __attribute__((ext_vector_type(8)));
typedef unsigned short u16x4 __attribute__((ext_vector_type(4)));
typedef unsigned short u16x8 __attribute__((ext_vector_type(8)));

__device__ __forceinline__ unsigned short f2bf_rne(float f) {
  unsigned u = __float_as_uint(f);
  u += 0x7FFFu + ((u >> 16) & 1u);
  return (unsigned short)(u >> 16);
}
__device__ __forceinline__ float bf2f(unsigned short h) {
  return __uint_as_float(((unsigned)h) << 16);
}

__device__ __forceinline__ void gld16(const void* gsrc, void* ldst) {
  typedef const unsigned int __attribute__((address_space(1))) GU;
  typedef unsigned int       __attribute__((address_space(3))) LU;
  __builtin_amdgcn_global_load_lds((GU*)(unsigned long long)gsrc,
                                   (LU*)(unsigned int)(unsigned long long)ldst,
                                   16, 0, 0);
}

// ---- shared top-2 helper (stable, lowest-index tie-break like lax.top_k)
__device__ __forceinline__ void top2_write(const float* acc, int t,
                                           int* __restrict__ topi,
                                           float* __restrict__ topw) {
  int i0 = 0; float l0 = acc[0];
#pragma unroll
  for (int e = 1; e < NEXP; e++) if (acc[e] > l0) { l0 = acc[e]; i0 = e; }
  int i1 = -1; float l1 = -3.4e38f;
#pragma unroll
  for (int e = 0; e < NEXP; e++) if (e != i0 && acc[e] > l1) { l1 = acc[e]; i1 = e; }
  float w0 = 1.f/(1.f + expf(l1 - l0));
  float w1 = 1.f/(1.f + expf(l0 - l1));
  topi[2*t]   = i0; topi[2*t+1] = i1;
  topw[2*t]   = w0; topw[2*t+1] = w1;
}

// ===== K1: FUSED x split (hi/lo) + gate/up routers (one pass over x) ======
__global__ __launch_bounds__(256) void split_router(
    const float* __restrict__ X,
    const float* __restrict__ RWg, const float* __restrict__ RWu,
    unsigned short* __restrict__ xhi, unsigned short* __restrict__ xlo,
    int* __restrict__ tig, float* __restrict__ twg,
    int* __restrict__ tiu, float* __restrict__ twu) {
  int lane = threadIdx.x & 63;
  int t = blockIdx.x*4 + (threadIdx.x>>6);
  const f32x4* xr = (const f32x4*)(X + (long)t*HDIM);
  u16x4* hr = (u16x4*)(xhi + (long)t*HDIM);
  u16x4* lr = (u16x4*)(xlo + (long)t*HDIM);
  float ag[NEXP], au[NEXP];
#pragma unroll
  for (int e = 0; e < NEXP; e++) { ag[e] = 0.f; au[e] = 0.f; }
#pragma unroll
  for (int it = 0; it < HDIM/4/64; it++) {   // 4
    int c4 = it*64 + lane;
    f32x4 xv = xr[c4];
    u16x4 hh, ll;
#pragma unroll
    for (int j = 0; j < 4; j++) {
      unsigned short hb = f2bf_rne(xv[j]);
      hh[j] = hb;
      ll[j] = f2bf_rne(xv[j] - bf2f(hb));
    }
    hr[c4] = hh; lr[c4] = ll;
#pragma unroll
    for (int j = 0; j < 4; j++) {
      const float* wg = RWg + (long)(c4*4+j)*NEXP;
      const float* wu = RWu + (long)(c4*4+j)*NEXP;
#pragma unroll
      for (int e = 0; e < NEXP; e++) { ag[e] += xv[j]*wg[e]; au[e] += xv[j]*wu[e]; }
    }
  }
#pragma unroll
  for (int e = 0; e < NEXP; e++) {
    float vg = ag[e], vu = au[e];
#pragma unroll
    for (int o = 1; o < 64; o <<= 1) { vg += __shfl_xor(vg, o); vu += __shfl_xor(vu, o); }
    ag[e] = vg; au[e] = vu;
  }
  if (lane == 0) { top2_write(ag, t, tig, twg); top2_write(au, t, tiu, twu); }
}

// ===== K2: ALL-IN-ONE vectorized transpose (gate, up, down in one grid) ===
__global__ void transpose_split3(const float* __restrict__ gex,
                                 unsigned short* __restrict__ wg_hi,
                                 unsigned short* __restrict__ wg_lo,
                                 const float* __restrict__ uex,
                                 unsigned short* __restrict__ wu_hi,
                                 unsigned short* __restrict__ wu_lo,
                                 const float* __restrict__ dex,
                                 unsigned short* __restrict__ wd_hi) {
  __shared__ float t[32][33];
  int z = blockIdx.z;
  const float* W; unsigned short *hi, *lo; int K, N, k0, n0;
  if (z < NEXP)        { W = gex; hi = wg_hi; lo = wg_lo; K = HDIM; N = IDIM;
                         n0 = blockIdx.x*32; k0 = blockIdx.y*32; }
  else if (z < 2*NEXP) { W = uex; hi = wu_hi; lo = wu_lo; K = HDIM; N = IDIM;
                         n0 = blockIdx.x*32; k0 = blockIdx.y*32; }
  else                 { W = dex; hi = wd_hi; lo = nullptr; K = IDIM; N = HDIM;
                         k0 = blockIdx.x*32; n0 = blockIdx.y*32; }
  long base = (long)(z & 7) * K * N;
  int id = threadIdx.y*8 + threadIdx.x;
  int lrr = id >> 3, lcq = id & 7;
  f32x4 v = *(const f32x4*)&W[base + (long)(k0+lrr)*N + n0 + lcq*4];
  t[lrr][lcq*4+0] = v[0]; t[lrr][lcq*4+1] = v[1];
  t[lrr][lcq*4+2] = v[2]; t[lrr][lcq*4+3] = v[3];
  __syncthreads();
  int n = threadIdx.y, kq = threadIdx.x;
  u16x4 h, l;
#pragma unroll
  for (int r = 0; r < 4; r++) {
    float f = t[kq*4+r][n];
    unsigned short hb = f2bf_rne(f);
    h[r] = hb;
    l[r] = f2bf_rne(f - bf2f(hb));
  }
  long o = base + (long)(n0+n)*K + k0 + kq*4;
  *(u16x4*)&hi[o] = h;
  if (lo) *(u16x4*)&lo[o] = l;
}

// ===== K4: deterministic stable per-expert compaction ====================
__device__ __forceinline__ void perm_body(const int* __restrict__ topi,
                                          const float* __restrict__ topw,
                                          int* __restrict__ offs,
                                          int* __restrict__ ptok,
                                          float* __restrict__ pw, int e) {
  int tid = threadIdx.x, lane = tid & 63, wv = tid >> 6;
  __shared__ int cnt[NEXP];
  __shared__ int wsum[4];
  if (tid < NEXP) cnt[tid] = 0;
  __syncthreads();
  for (int p = tid; p < NPAIR; p += 256) atomicAdd(&cnt[topi[p]], 1);
  __syncthreads();
  int base = 0;
#pragma unroll
  for (int e2 = 0; e2 < NEXP; e2++) if (e2 < e) base += cnt[e2];
  if (tid == 0) { offs[e] = base; if (e == NEXP-1) offs[NEXP] = base + cnt[e]; }
  for (int p0 = 0; p0 < NPAIR; p0 += 256) {
    int p = p0 + tid;
    bool m = (topi[p] == e);
    unsigned long long b = __ballot(m);
    int lp = __popcll(b & ((1ull << lane) - 1ull));
    if (lane == 0) wsum[wv] = __popcll(b);
    __syncthreads();
    int woff = 0;
#pragma unroll
    for (int w2 = 0; w2 < 4; w2++) if (w2 < wv) woff += wsum[w2];
    int tot = wsum[0] + wsum[1] + wsum[2] + wsum[3];
    if (m) { int dst = base + woff + lp; ptok[dst] = p >> 1; pw[dst] = topw[p]; }
    base += tot;
    __syncthreads();
  }
}
__global__ __launch_bounds__(256) void build_perm(const int* topi, const float* topw,
                                                  int* offs, int* ptok, float* pw) {
  perm_body(topi, topw, offs, ptok, pw, blockIdx.x);
}
__global__ __launch_bounds__(256) void build_perm2(
    const int* tig, const float* twg, int* offsg, int* ptokg, float* pwg,
    const int* tiu, const float* twu, int* offsu, int* ptoku, float* pwu) {
  if (blockIdx.x < NEXP) perm_body(tig, twg, offsg, ptokg, pwg, blockIdx.x);
  else                   perm_body(tiu, twu, offsu, ptoku, pwu, blockIdx.x - NEXP);
}

// ===== K5: gathered 3-term GEMM, 256x256 MACRO-TILE (measured best: 447us)
// R8/R12 structure: per K-step stage all 4 planes into dbuf (each plane
// streamed from HBM once per block; FETCH 474MB, conflicts 0), 3 phase-
// clusters of 32 MFMA (hihi -> hilo -> lohi), single __syncthreads per tile.
// Five schedule-surgery attempts (R7/R9/R11/R13) all landed >= this: this is
// the measured optimum of the family — plateau.
__global__ __launch_bounds__(512) void moe_gemm3_mt(
    const unsigned short* __restrict__ Ahi, const unsigned short* __restrict__ Alo,
    const unsigned short* __restrict__ Bhi, const unsigned short* __restrict__ Blo,
    const int* __restrict__ offs, const int* __restrict__ ptok,
    const float* __restrict__ pw, float* __restrict__ out)
{
  const int e = blockIdx.z;
  const int beg = offs[e];
  const int cnt = offs[e+1] - beg;
  const int m0 = blockIdx.y * 256;   // NO XCD swizzle (round-3 lesson)
  if (m0 >= cnt) return;
  const int n0 = blockIdx.x * 256;

  __shared__ unsigned short As[2][2][256*32];  // [buf][hi/lo]  64KB
  __shared__ unsigned short Bs[2][2][256*32];  // 64KB
  __shared__ int   stok[256];
  __shared__ float swt[256];

  const int tid = threadIdx.x, lane = tid & 63, wv = tid >> 6;
  if (tid < 256) {
    int i = m0 + tid;
    stok[tid] = ptok[beg + (i < cnt ? i : 0)];
    swt[tid]  = (i < cnt) ? pw[beg + i] : 0.f;
  }
  __syncthreads();

  const int srow = lane >> 2;
  const int lc   = ((lane & 3) - ((lane >> 3) & 3)) & 3;  // pre-swizzled src
  const long aoff0 = (long)stok[wv*32 +      srow]*HDIM + lc*8;
  const long aoff1 = (long)stok[wv*32 + 16 + srow]*HDIM + lc*8;
  const long boff0 = ((long)e*IDIM + n0 + wv*32 +      srow)*HDIM + lc*8;
  const long boff1 = ((long)e*IDIM + n0 + wv*32 + 16 + srow)*HDIM + lc*8;
  const int dst0 = (wv*32     )*32;
  const int dst1 = (wv*32 + 16)*32;

#define STAGE_A(buf, kk) do {                                   \
    int kl_ = (kk)*32;                                          \
    gld16(Ahi + aoff0 + kl_, &As[buf][0][dst0]);                \
    gld16(Ahi + aoff1 + kl_, &As[buf][0][dst1]);                \
    gld16(Alo + aoff0 + kl_, &As[buf][1][dst0]);                \
    gld16(Alo + aoff1 + kl_, &As[buf][1][dst1]);                \
  } while (0)
#define STAGE_B(buf, kk) do {                                   \
    int kl_ = (kk)*32;                                          \
    gld16(Bhi + boff0 + kl_, &Bs[buf][0][dst0]);                \
    gld16(Bhi + boff1 + kl_, &Bs[buf][0][dst1]);                \
    gld16(Blo + boff0 + kl_, &Bs[buf][1][dst0]);                \
    gld16(Blo + boff1 + kl_, &Bs[buf][1][dst1]);                \
  } while (0)

  const int fl = lane & 15, fg = lane >> 4;
  const int pks = (((fg + (fl >> 1)) & 3) << 3);
  const int wm = wv >> 2, wn = wv & 3;   // 2M x 4N wave grid
  const int arow = wm * 128;
  const int bcol = wn * 64;

  f32x4 acc[8][4];
#pragma unroll
  for (int m = 0; m < 8; m++)
#pragma unroll
    for (int n = 0; n < 4; n++) acc[m][n] = {0.f, 0.f, 0.f, 0.f};

  STAGE_A(0, 0);
  STAGE_B(0, 0);
  __syncthreads();

  int cur = 0;
  for (int kt = 0; kt < HDIM/BK; ++kt) {   // 32 macro-tiles
    const bool st = (kt + 1 < HDIM/BK);
    s16x8 ahf[8], bhi4[4], blo4[4];

    // phase A: issue A(t+1) | read Ahi[8]+Bhi[4]+Blo[4] | 32 MFMA hi*hi
    if (st) STAGE_A(cur^1, kt + 1);
#pragma unroll
    for (int n = 0; n < 4; n++)
      bhi4[n] = *(const s16x8*)&Bs[cur][0][(bcol + n*16 + fl)*32 + pks];
#pragma unroll
    for (int n = 0; n < 4; n++)
      blo4[n] = *(const s16x8*)&Bs[cur][1][(bcol + n*16 + fl)*32 + pks];
#pragma unroll
    for (int i = 0; i < 8; i++)
      ahf[i] = *(const s16x8*)&As[cur][0][(arow + i*16 + fl)*32 + pks];
    __builtin_amdgcn_s_setprio(1);
#pragma unroll
    for (int i = 0; i < 8; i++)
#pragma unroll
      for (int n = 0; n < 4; n++)
        acc[i][n] = __builtin_amdgcn_mfma_f32_16x16x32_bf16(ahf[i], bhi4[n], acc[i][n], 0,0,0);
    __builtin_amdgcn_s_setprio(0);

    // phase B: issue B(t+1) | 32 MFMA hi*lo (regs live, no reads)
    if (st) STAGE_B(cur^1, kt + 1);
    __builtin_amdgcn_s_setprio(1);
#pragma unroll
    for (int i = 0; i < 8; i++)
#pragma unroll
      for (int n = 0; n < 4; n++)
        acc[i][n] = __builtin_amdgcn_mfma_f32_16x16x32_bf16(ahf[i], blo4[n], acc[i][n], 0,0,0);
    __builtin_amdgcn_s_setprio(0);

    // phase C: read Alo[8] (reuse ahf regs) | 32 MFMA lo*hi
#pragma unroll
    for (int i = 0; i < 8; i++)
      ahf[i] = *(const s16x8*)&As[cur][1][(arow + i*16 + fl)*32 + pks];
    __builtin_amdgcn_s_setprio(1);
#pragma unroll
    for (int i = 0; i < 8; i++)
#pragma unroll
      for (int n = 0; n < 4; n++)
        acc[i][n] = __builtin_amdgcn_mfma_f32_16x16x32_bf16(ahf[i], bhi4[n], acc[i][n], 0,0,0);
    __builtin_amdgcn_s_setprio(0);

    __syncthreads();   // drains vmcnt: t+1 landed; everyone done with cur
    cur ^= 1;
  }
#undef STAGE_A
#undef STAGE_B

  // epilogue: C/D map col=lane&15, row=(lane>>4)*4+r  [m89/m91-verified]
#pragma unroll
  for (int m = 0; m < 8; m++)
#pragma unroll
    for (int r = 0; r < 4; r++) {
      int lrow = arow + m*16 + fg*4 + r;
      if (m0 + lrow < cnt) {
        float wt = swt[lrow];
        long ob = (long)stok[lrow]*IDIM + n0 + bcol + fl;
#pragma unroll
        for (int n = 0; n < 4; n++)
          atomicAdd(&out[ob + n*16], wt * acc[m][n][r]);
      }
    }
}

// ===== K6: fused SwiGLU + down-router; writes h as bf16 (RNE) =============
__global__ __launch_bounds__(256) void swiglu_router_bf(
    const float* __restrict__ g, const float* __restrict__ u,
    unsigned short* __restrict__ hb,
    const float* __restrict__ RW,
    int* __restrict__ topi, float* __restrict__ topw) {
  int lane = threadIdx.x & 63;
  int t = blockIdx.x*4 + (threadIdx.x>>6);
  const f32x4* gr = (const f32x4*)(g + (long)t*IDIM);
  const f32x4* ur = (const f32x4*)(u + (long)t*IDIM);
  u16x4*       hr = (u16x4*)(hb + (long)t*IDIM);
  float acc[NEXP];
#pragma unroll
  for (int e = 0; e < NEXP; e++) acc[e] = 0.f;
#pragma unroll
  for (int it = 0; it < IDIM/4/64; it++) {   // 14
    int c4 = it*64 + lane;
    f32x4 gv = gr[c4], uv = ur[c4], hv;
    u16x4 hh;
#pragma unroll
    for (int j = 0; j < 4; j++) {
      float x = gv[j];
      hv[j] = x * uv[j] / (1.f + expf(-x));
      hh[j] = f2bf_rne(hv[j]);
    }
    hr[c4] = hh;
#pragma unroll
    for (int j = 0; j < 4; j++) {
      const float* wr = RW + (long)(c4*4+j)*NEXP;
#pragma unroll
      for (int e = 0; e < NEXP; e++) acc[e] += hv[j]*wr[e];
    }
  }
#pragma unroll
  for (int e = 0; e < NEXP; e++) {
    float v = acc[e];
#pragma unroll
    for (int o = 1; o < 64; o <<= 1) v += __shfl_xor(v, o);
    acc[e] = v;
  }
  if (lane == 0) top2_write(acc, t, topi, topw);
}

// ===== K7: down GEMM, both operands bf16 gld16-staged, dbuf + swizzle =====
__global__ __launch_bounds__(256) void moe_gemm_down_bf(
    const unsigned short* __restrict__ Hb, const unsigned short* __restrict__ Bw,
    const int* __restrict__ offs, const int* __restrict__ ptok,
    const float* __restrict__ pw, float* __restrict__ out)
{
  const int K = IDIM, N = HDIM;
  const int e = blockIdx.z;
  const int beg = offs[e];
  const int cnt = offs[e+1] - beg;
  const int m0 = blockIdx.y * 128;   // NO swizzle
  if (m0 >= cnt) return;
  const int n0 = blockIdx.x * 128;

  __shared__ unsigned short As[2][128*32], Bs[2][128*32];  // 32KB dbuf
  __shared__ int   stok[128];
  __shared__ float swt[128];

  const int tid = threadIdx.x, lane = tid & 63, wv = tid >> 6;  // 4 waves
  if (tid < 128) {
    int i = m0 + tid;
    stok[tid] = ptok[beg + (i < cnt ? i : 0)];
    swt[tid]  = (i < cnt) ? pw[beg + i] : 0.f;
  }
  __syncthreads();

  const int srow = lane >> 2;
  const int lc   = ((lane & 3) - ((lane >> 3) & 3)) & 3;
  const long aoff0 = (long)stok[wv*32 +      srow]*K + lc*8;
  const long aoff1 = (long)stok[wv*32 + 16 + srow]*K + lc*8;
  const long boff0 = ((long)e*N + n0 + wv*32 +      srow)*K + lc*8;
  const long boff1 = ((long)e*N + n0 + wv*32 + 16 + srow)*K + lc*8;
  const int dst0 = (wv*32     )*32;
  const int dst1 = (wv*32 + 16)*32;

#define STAGE(buf, kt) do {                                 \
    int kl_ = (kt)*32;                                      \
    gld16(Hb + aoff0 + kl_, &As[buf][dst0]);                \
    gld16(Hb + aoff1 + kl_, &As[buf][dst1]);                \
    gld16(Bw + boff0 + kl_, &Bs[buf][dst0]);                \
    gld16(Bw + boff1 + kl_, &Bs[buf][dst1]);                \
  } while (0)

  const int fl = lane & 15, fg = lane >> 4;
  const int pks = (((fg + (fl >> 1)) & 3) << 3);
  const int arow = (wv >> 1)*64, bcol = (wv & 1)*64;

  f32x4 acc[4][4];
#pragma unroll
  for (int m = 0; m < 4; m++)
#pragma unroll
    for (int n = 0; n < 4; n++) acc[m][n] = {0.f, 0.f, 0.f, 0.f};

  STAGE(0, 0);
  __syncthreads();

  int cur = 0;
  for (int kt = 0; kt < K/BK; ++kt) {   // 112
    if (kt + 1 < K/BK) STAGE(cur^1, kt + 1);

    s16x8 ahf[4], bhf[4];
#pragma unroll
    for (int i = 0; i < 4; i++) {
      ahf[i] = *(const s16x8*)&As[cur][(arow + i*16 + fl)*32 + pks];
      bhf[i] = *(const s16x8*)&Bs[cur][(bcol + i*16 + fl)*32 + pks];
    }
    __builtin_amdgcn_s_setprio(1);
#pragma unroll
    for (int i = 0; i < 4; i++)
#pragma unroll
      for (int n = 0; n < 4; n++)
        acc[i][n] = __builtin_amdgcn_mfma_f32_16x16x32_bf16(ahf[i], bhf[n], acc[i][n], 0,0,0);
    __builtin_amdgcn_s_setprio(0);

    __syncthreads();
    cur ^= 1;
  }
#undef STAGE

#pragma unroll
  for (int m = 0; m < 4; m++)
#pragma unroll
    for (int r = 0; r < 4; r++) {
      int lrow = arow + m*16 + fg*4 + r;
      if (m0 + lrow < cnt) {
        float wt = swt[lrow];
        long ob = (long)stok[lrow]*N + n0 + bcol + fl;
#pragma unroll
        for (int n = 0; n < 4; n++)
          atomicAdd(&out[ob + n*16], wt * acc[m][n][r]);
      }
    }
}

// ========================== host launcher =================================
// Workspace plan (469.8MB avail; peak ~445.6MB). Aliases:
//   ubuf (f32, 117.4MB) = wg_hi+wg_lo region — memset AFTER gate GEMM.
//   hbuf (bf16, 58.7MB) = wu_lo — written by swiglu AFTER up GEMM.
extern "C" void kernel_launch(void* const* d_in, const int* in_sizes, int n_in,
                              void* d_out, int out_size, void* d_ws, size_t ws_size,
                              hipStream_t stream)
{
  (void)in_sizes; (void)n_in;
  const float* x   = (const float*)d_in[0];
  const float* grt = (const float*)d_in[1];
  const float* gex = (const float*)d_in[2];
  const float* urt = (const float*)d_in[3];
  const float* uex = (const float*)d_in[4];
  const float* drt = (const float*)d_in[5];
  const float* dex = (const float*)d_in[6];
  float* out = (float*)d_out;

  char* base = (char*)d_ws;
  size_t off = 0;
  auto alloc = [&](size_t b) -> void* {
    void* r = base + off;
    off = (off + b + 255) & ~(size_t)255;
    return r;
  };
  const size_t szXH = (size_t)T_TOK*HDIM*2;          // 16.78 MB
  const size_t szW  = (size_t)NEXP*HDIM*IDIM*2;      // 58.72 MB
  const size_t szGI = (size_t)T_TOK*IDIM*4;          // 117.44 MB

  unsigned short* xhi   = (unsigned short*)alloc(szXH);
  unsigned short* xlo   = (unsigned short*)alloc(szXH);
  unsigned short* wg_hi = (unsigned short*)alloc(szW);   // later: ubuf (f32)
  unsigned short* wg_lo = (unsigned short*)alloc(szW);
  unsigned short* wu_hi = (unsigned short*)alloc(szW);
  unsigned short* wu_lo = (unsigned short*)alloc(szW);   // later: hbuf (bf16)
  unsigned short* wd_hi = (unsigned short*)alloc(szW);
  float* gbuf = (float*)alloc(szGI);
  int*   topi_g = (int*)alloc(NPAIR*4);  float* topw_g = (float*)alloc(NPAIR*4);
  int*   topi_u = (int*)alloc(NPAIR*4);  float* topw_u = (float*)alloc(NPAIR*4);
  int*   topi_d = (int*)alloc(NPAIR*4);  float* topw_d = (float*)alloc(NPAIR*4);
  int* offs_g = (int*)alloc(64);
  int* offs_u = (int*)alloc(64);
  int* offs_d = (int*)alloc(64);
  int*   ptok_g = (int*)alloc(NPAIR*4);  float* pw_g = (float*)alloc(NPAIR*4);
  int*   ptok_u = (int*)alloc(NPAIR*4);  float* pw_u = (float*)alloc(NPAIR*4);
  int*   ptok_d = (int*)alloc(NPAIR*4);  float* pw_d = (float*)alloc(NPAIR*4);

  float*          ubuf = (float*)wg_hi;   // spans wg_hi+wg_lo (contiguous)
  unsigned short* hbuf = wu_lo;

  if (off > ws_size) {
    fprintf(stderr, "[moe] ws too small: need %zu bytes, have %zu\n", off, ws_size);
    hipMemsetAsync(d_out, 0, (size_t)out_size*sizeof(float), stream);
    return;
  }

  hipMemsetAsync(gbuf, 0, szGI, stream);
  hipMemsetAsync(d_out, 0, (size_t)out_size*sizeof(float), stream);

  transpose_split3<<<dim3(IDIM/32, HDIM/32, 3*NEXP), dim3(8,32), 0, stream>>>(
      gex, wg_hi, wg_lo, uex, wu_hi, wu_lo, dex, wd_hi);
  split_router<<<T_TOK/4, 256, 0, stream>>>(x, grt, urt, xhi, xlo,
                                            topi_g, topw_g, topi_u, topw_u);
  build_perm2<<<2*NEXP, 256, 0, stream>>>(topi_g, topw_g, offs_g, ptok_g, pw_g,
                                          topi_u, topw_u, offs_u, ptok_u, pw_u);

  // gate GEMM (last reader of wg region)
  moe_gemm3_mt<<<dim3(IDIM/256, 32, NEXP), 512, 0, stream>>>(
      xhi, xlo, wg_hi, wg_lo, offs_g, ptok_g, pw_g, gbuf);

  // wg region dead -> ubuf
  hipMemsetAsync(ubuf, 0, szGI, stream);
  moe_gemm3_mt<<<dim3(IDIM/256, 32, NEXP), 512, 0, stream>>>(
      xhi, xlo, wu_hi, wu_lo, offs_u, ptok_u, pw_u, ubuf);

  // fused: h = silu(g)*u -> bf16 hbuf + down-router top2 (on exact f32 h)
  swiglu_router_bf<<<T_TOK/4, 256, 0, stream>>>(gbuf, ubuf, hbuf, drt, topi_d, topw_d);
  build_perm<<<NEXP, 256, 0, stream>>>(topi_d, topw_d, offs_d, ptok_d, pw_d);

  moe_gemm_down_bf<<<dim3(HDIM/128, 64, NEXP), 256, 0, stream>>>(
      hbuf, wd_hi, offs_d, ptok_d, pw_d, out);
}